// Round 4
// baseline (4239.597 us; speedup 1.0000x reference)
//
#include <hip/hip_runtime.h>

// HGTPolicy: 2-layer heterogeneous graph transformer + pooling + value/policy heads.
// All tensors float32 per the reference. Internal compute f32.

// ---------------- zero fill ----------------
__global__ void k_zero(float* p, int n) {
    int i = blockIdx.x * 256 + threadIdx.x;
    int stride = gridDim.x * 256;
    for (; i < n; i += stride) p[i] = 0.0f;
}

// ---------------- initial embedding + moment accumulation ----------------
// one block (64 threads) per node
__global__ void k_embed(const float* x, const float* W, const float* b,
                        int F, float* X, float* acc) {
    __shared__ float s1[64];
    __shared__ float s2[64];
    int n = blockIdx.x, j = threadIdx.x;
    const float* xr = x + (size_t)n * F;
    float a = b[j];
    for (int k = 0; k < F; k++) a += xr[k] * W[k * 64 + j];
    X[(size_t)n * 64 + j] = a;
    s1[j] = a;
    s2[j] = a * a;
    __syncthreads();
    for (int o = 32; o > 0; o >>= 1) {
        if (j < o) { s1[j] += s1[j + o]; s2[j] += s2[j + o]; }
        __syncthreads();
    }
    if (j == 0) { atomicAdd(&acc[0], s1[0]); atomicAdd(&acc[1], s2[0]); }
}

// ---------------- graph-norm over all N*64 elements of one node type ----------
__global__ void k_gnorm(float* X, const float* acc, const float* gamma,
                        const float* beta, int N) {
    int i = blockIdx.x * 256 + threadIdx.x;
    int tot = N * 64;
    if (i >= tot) return;
    float inv = 1.0f / (float)tot;
    float mu  = acc[0] * inv;
    float var = acc[1] * inv - mu * mu;
    float sd  = sqrtf(fmaxf(var, 0.0f));
    float sc  = 1.0f / (sd + 1e-5f);
    int j = i & 63;
    X[i] = (X[i] - mu) * sc * gamma[j] + beta[j];
}

// ---------------- KQV projection: [64] -> [192], one block/node ----------------
__global__ void k_kqv(const float* X, const float* Wkqv, const float* bkqv,
                      float* KQV, int N0, int N1, int l) {
    int n = blockIdx.x, j = threadIdx.x;   // 192 threads
    int t = (n < N0) ? 0 : ((n < N0 + N1) ? 1 : 2);
    const float* W = Wkqv + (size_t)(l * 3 + t) * 64 * 192;
    const float* b = bkqv + (size_t)(l * 3 + t) * 192;
    __shared__ float xs[64];
    if (j < 64) xs[j] = X[(size_t)n * 64 + j];
    __syncthreads();
    float a = b[j];
    for (int k = 0; k < 64; k++) a += xs[k] * W[k * 192 + j];
    KQV[(size_t)n * 192 + j] = a;
}

// attention logit for (edge, head): q_dst . (k_src @ krel) * prel / sqrt(8)
__device__ __forceinline__ float attn_logit(const float* KQV, int sn, int dn,
                                            int h, const float* KR8, const float* PR) {
    const float* kr = KQV + (size_t)sn * 192 + h * 8;
    const float* qr = KQV + (size_t)dn * 192 + 64 + h * 8;
    const float* KR = KR8 + h * 64;        // krel[l][e][h] : [8][8] (d, e')
    float a = 0.0f;
#pragma unroll
    for (int ee = 0; ee < 8; ee++) {
        float ke = 0.0f;
#pragma unroll
        for (int d = 0; d < 8; d++) ke += kr[d] * KR[d * 8 + ee];
        a += qr[ee] * ke;
    }
    return a * PR[h] * 0.35355339059327373f;
}

// ---- pass A: softmax denominator (no max-shift; logits O(1) post-graphnorm) ----
__global__ void k_den(const float* KQV, const int* esrc, const int* edst,
                      int E, int soff, int doff, const float* KR8, const float* PR,
                      float* den) {
    int tid = blockIdx.x * 256 + threadIdx.x;
    if (tid >= E * 8) return;
    int i = tid >> 3, h = tid & 7;
    int sn = esrc[i] + soff;
    int dn = edst[i] + doff;
    float ex = expf(attn_logit(KQV, sn, dn, h, KR8, PR));
    atomicAdd(&den[(size_t)dn * 8 + h], ex);
}

// ---- pass B: recompute weight, aggregate v@vrel messages into agg ----
__global__ void k_aggr(const float* KQV, const int* esrc, const int* edst,
                       int E, int soff, int doff, const float* KR8, const float* VR8,
                       const float* PR, const float* den, float* agg) {
    int tid = blockIdx.x * 256 + threadIdx.x;
    if (tid >= E * 8) return;
    int i = tid >> 3, h = tid & 7;
    int sn = esrc[i] + soff;
    int dn = edst[i] + doff;
    float ex = expf(attn_logit(KQV, sn, dn, h, KR8, PR));
    float w = ex / den[(size_t)dn * 8 + h];
    const float* vr = KQV + (size_t)sn * 192 + 128 + h * 8;
    const float* VR = VR8 + h * 64;
#pragma unroll
    for (int ee = 0; ee < 8; ee++) {
        float ve = 0.0f;
#pragma unroll
        for (int d = 0; d < 8; d++) ve += vr[d] * VR[d * 8 + ee];
        atomicAdd(&agg[(size_t)dn * 64 + h * 8 + ee], w * ve);
    }
}

// ---------------- output projection + skip gate (in place) ----------------
__global__ void k_out(const float* agg, float* X, const float* Wout,
                      const float* bout, const float* skip, int N0, int N1, int l) {
    int n = blockIdx.x, j = threadIdx.x;   // 64 threads
    int t = (n < N0) ? 0 : ((n < N0 + N1) ? 1 : 2);
    const float* W = Wout + (size_t)(l * 3 + t) * 64 * 64;
    const float* b = bout + (size_t)(l * 3 + t) * 64;
    __shared__ float ga[64];
    float x = agg[(size_t)n * 64 + j];
    ga[j] = 0.5f * x * (1.0f + erff(x * 0.70710678118654752f));  // exact gelu
    float xold = X[(size_t)n * 64 + j];
    __syncthreads();
    float o = b[j];
    for (int k = 0; k < 64; k++) o += ga[k] * W[k * 64 + j];
    float gk = 1.0f / (1.0f + expf(-skip[l * 3 + t]));
    X[(size_t)n * 64 + j] = gk * o + (1.0f - gk) * xold;
}

// ---------------- global mean pooling (sum; divide in k_value) ----------------
__global__ void k_pool(const float* X, float* gsum, int N0, int N1, int N2) {
    int t = blockIdx.y, j = threadIdx.x;   // 64 threads
    int N   = (t == 0) ? N0 : ((t == 1) ? N1 : N2);
    int off = (t == 0) ? 0  : ((t == 1) ? N0 : N0 + N1);
    const float* base = X + (size_t)off * 64;
    float s = 0.0f;
    for (int r = blockIdx.x; r < N; r += gridDim.x) s += base[(size_t)r * 64 + j];
    atomicAdd(&gsum[t * 64 + j], s);
}

// ---------------- value head (one block, 192 threads) ----------------
__global__ void k_value(const float* gsum, float* gvec, const float* Wv1,
                        const float* bv1, const float* Wv2, const float* bv2,
                        float* out_val, int N0, int N1, int N2) {
    __shared__ float g[192];
    __shared__ float h1[64];
    int j = threadIdx.x;
    float Nd = (j < 64) ? (float)N0 : ((j < 128) ? (float)N1 : (float)N2);
    float gv = gsum[j] / Nd;
    g[j] = gv;
    gvec[j] = gv;
    __syncthreads();
    if (j < 64) {
        float a = bv1[j];
        for (int k = 0; k < 192; k++) a += g[k] * Wv1[k * 64 + j];
        h1[j] = fmaxf(a, 0.0f);
    }
    __syncthreads();
    if (j == 0) {
        float v = bv2[0];
        for (int k = 0; k < 64; k++) v += h1[k] * Wv2[k];
        out_val[0] = v;
    }
}

// ---------------- policy head (one block of 64 per pair) ----------------
__global__ void HGTPolicy_53051436040798_kernel(
        const float* X, const float* gvec, const int* op_idx, const int* m_idx,
        const float* Wp1, const float* bp1, const float* Wp2, const float* bp2,
        const float* Wp3, const float* bp3, float* out, int N0) {
    int p = blockIdx.x, j = threadIdx.x;   // 64 threads
    __shared__ float z[320];
    __shared__ float h1[64];
    __shared__ float h2[32];
    int on = op_idx[p], mn = m_idx[p];
    z[j]       = X[(size_t)on * 64 + j];
    z[64 + j]  = X[(size_t)(N0 + mn) * 64 + j];
    z[128 + j] = gvec[j];
    z[192 + j] = gvec[64 + j];
    z[256 + j] = gvec[128 + j];
    __syncthreads();
    float a = bp1[j];
    for (int k = 0; k < 320; k++) a += z[k] * Wp1[k * 64 + j];
    h1[j] = fmaxf(a, 0.0f);
    __syncthreads();
    if (j < 32) {
        float a2 = bp2[j];
        for (int k = 0; k < 64; k++) a2 += h1[k] * Wp2[k * 32 + j];
        h2[j] = fmaxf(a2, 0.0f);
    }
    __syncthreads();
    if (j == 0) {
        float lg = bp3[0];
        for (int k = 0; k < 32; k++) lg += h2[k] * Wp3[k];
        out[p] = lg;
    }
}

extern "C" void kernel_launch(void* const* d_in, const int* in_sizes, int n_in,
                              void* d_out, int out_size, void* d_ws, size_t ws_size,
                              hipStream_t stream) {
    const float* op_x      = (const float*)d_in[0];
    const float* machine_x = (const float*)d_in[1];
    const float* job_x     = (const float*)d_in[2];
    const float* W_op   = (const float*)d_in[3];
    const float* b_op   = (const float*)d_in[4];
    const float* W_mach = (const float*)d_in[5];
    const float* b_mach = (const float*)d_in[6];
    const float* W_job  = (const float*)d_in[7];
    const float* b_job  = (const float*)d_in[8];
    const float* ln_gamma = (const float*)d_in[9];
    const float* ln_beta  = (const float*)d_in[10];
    const float* Wkqv = (const float*)d_in[11];
    const float* bkqv = (const float*)d_in[12];
    const float* krel = (const float*)d_in[13];
    const float* vrel = (const float*)d_in[14];
    const float* prel = (const float*)d_in[15];
    const float* Wout = (const float*)d_in[16];
    const float* bout = (const float*)d_in[17];
    const float* skip = (const float*)d_in[18];
    const float* Wp1 = (const float*)d_in[19];
    const float* bp1 = (const float*)d_in[20];
    const float* Wp2 = (const float*)d_in[21];
    const float* bp2 = (const float*)d_in[22];
    const float* Wp3 = (const float*)d_in[23];
    const float* bp3 = (const float*)d_in[24];
    const float* Wv1 = (const float*)d_in[25];
    const float* bv1 = (const float*)d_in[26];
    const float* Wv2 = (const float*)d_in[27];
    const float* bv2 = (const float*)d_in[28];
    const int* op_idx = (const int*)d_in[37];
    const int* m_idx  = (const int*)d_in[38];

    const int NOP = in_sizes[0] / 8;
    const int NM  = in_sizes[1] / 7;
    const int NJ  = in_sizes[2] / 7;
    const int L   = in_sizes[11] / (3 * 64 * 192);
    const int P   = in_sizes[37];
    const int Ntot = NOP + NM + NJ;

    // EDGE_DEFS: (src_type, dst_type)
    const int sdef[8] = {2, 0, 0, 0, 0, 0, 1, 1};
    const int ddef[8] = {0, 2, 0, 0, 1, 1, 0, 0};
    const int toff[3] = {0, NOP, NOP + NM};
    const int* eptr[8];
    int Esz[8];
    for (int e = 0; e < 8; e++) {
        Esz[e] = in_sizes[29 + e] / 2;
        eptr[e] = (const int*)d_in[29 + e];
    }

    // workspace layout (f32 elements), ~74 MB
    float* ws = (float*)d_ws;
    size_t o = 0;
    float* X    = ws + o; o += (size_t)Ntot * 64;
    float* KQV  = ws + o; o += (size_t)Ntot * 192;
    float* agg  = ws + o; o += (size_t)Ntot * 64;   // agg, den contiguous: one zero-fill
    float* den  = ws + o; o += (size_t)Ntot * 8;
    float* gsum = ws + o; o += 192;                 // gsum, gvec, nacc contiguous
    float* gvec = ws + o; o += 192;
    float* nacc = ws + o; o += 8;

    // zero small accumulators (gsum + gvec + nacc = 392 floats)
    k_zero<<<1, 256, 0, stream>>>(gsum, 392);

    // embed + per-type graph-norm
    k_embed<<<NOP, 64, 0, stream>>>(op_x,      W_op,   b_op,   8, X,                           nacc + 0);
    k_embed<<<NM,  64, 0, stream>>>(machine_x, W_mach, b_mach, 7, X + (size_t)NOP * 64,        nacc + 2);
    k_embed<<<NJ,  64, 0, stream>>>(job_x,     W_job,  b_job,  7, X + (size_t)(NOP + NM) * 64, nacc + 4);

    k_gnorm<<<(NOP * 64 + 255) / 256, 256, 0, stream>>>(X, nacc + 0, ln_gamma, ln_beta, NOP);
    k_gnorm<<<(NM * 64 + 255) / 256, 256, 0, stream>>>(X + (size_t)NOP * 64, nacc + 2,
                                                       ln_gamma + 64, ln_beta + 64, NM);
    k_gnorm<<<(NJ * 64 + 255) / 256, 256, 0, stream>>>(X + (size_t)(NOP + NM) * 64, nacc + 4,
                                                       ln_gamma + 128, ln_beta + 128, NJ);

    for (int l = 0; l < L; l++) {
        k_zero<<<2048, 256, 0, stream>>>(agg, Ntot * 72);   // agg + den
        k_kqv<<<Ntot, 192, 0, stream>>>(X, Wkqv, bkqv, KQV, NOP, NM, l);
        for (int e = 0; e < 8; e++) {
            int E = Esz[e];
            const float* KR8 = krel + (size_t)(l * 8 + e) * 512;  // 8 heads * 8 * 8
            const float* PR  = prel + (size_t)(l * 8 + e) * 8;
            k_den<<<(E * 8 + 255) / 256, 256, 0, stream>>>(
                KQV, eptr[e], eptr[e] + E, E, toff[sdef[e]], toff[ddef[e]], KR8, PR, den);
        }
        for (int e = 0; e < 8; e++) {
            int E = Esz[e];
            const float* KR8 = krel + (size_t)(l * 8 + e) * 512;
            const float* VR8 = vrel + (size_t)(l * 8 + e) * 512;
            const float* PR  = prel + (size_t)(l * 8 + e) * 8;
            k_aggr<<<(E * 8 + 255) / 256, 256, 0, stream>>>(
                KQV, eptr[e], eptr[e] + E, E, toff[sdef[e]], toff[ddef[e]],
                KR8, VR8, PR, den, agg);
        }
        k_out<<<Ntot, 64, 0, stream>>>(agg, X, Wout, bout, skip, NOP, NM, l);
    }

    // pooling + heads
    dim3 pg(64, 3);
    k_pool<<<pg, 64, 0, stream>>>(X, gsum, NOP, NM, NJ);
    k_value<<<1, 192, 0, stream>>>(gsum, gvec, Wv1, bv1, Wv2, bv2,
                                   (float*)d_out + P, NOP, NM, NJ);
    HGTPolicy_53051436040798_kernel<<<P, 64, 0, stream>>>(
        X, gvec, op_idx, m_idx, Wp1, bp1, Wp2, bp2, Wp3, bp3, (float*)d_out, NOP);
}

// Round 5
// 1039.377 us; speedup vs baseline: 4.0790x; 4.0790x over previous
//
#include <hip/hip_runtime.h>

// HGTPolicy: 2-layer heterogeneous graph transformer + pooling + value/policy heads.
// All tensors float32. Round-5: CSR-based fused attention-aggregation (no output atomics).

// ---------------- zero fill (u32) ----------------
__global__ void k_zero(unsigned int* p, int n) {
    int i = blockIdx.x * 256 + threadIdx.x;
    int stride = gridDim.x * 256;
    for (; i < n; i += stride) p[i] = 0u;
}

// ---------------- edge flattening + dst histogram ----------------
__global__ void k_flat(const int* epair, int E, int soff, int doff, int et, int eoff,
                       int* gdst, int* pack, int* cnt) {
    int i = blockIdx.x * 256 + threadIdx.x;
    if (i >= E) return;
    int gs = epair[i] + soff;
    int gd = epair[E + i] + doff;
    gdst[eoff + i] = gd;
    pack[eoff + i] = gs | (et << 24);
    atomicAdd(&cnt[gd], 1);
}

// ---------------- two-level exclusive scan of cnt[Ntot] ----------------
__global__ void k_scan1(const int* cnt, int* partial, int Ntot) {
    __shared__ int s[256];
    int t = threadIdx.x;
    int i = blockIdx.x * 256 + t;
    s[t] = (i < Ntot) ? cnt[i] : 0;
    __syncthreads();
    for (int o = 128; o > 0; o >>= 1) {
        if (t < o) s[t] += s[t + o];
        __syncthreads();
    }
    if (t == 0) partial[blockIdx.x] = s[0];
}

__global__ void k_scan2(int* partial, int nchunks) {
    if (threadIdx.x == 0 && blockIdx.x == 0) {
        int run = 0;
        for (int c = 0; c < nchunks; c++) { int v = partial[c]; partial[c] = run; run += v; }
    }
}

__global__ void k_scan3(const int* cnt, const int* partial, int* rowptr, int* cursor,
                        int Ntot, int Etot) {
    __shared__ int s[256];
    int t = threadIdx.x;
    int i = blockIdx.x * 256 + t;
    int v = (i < Ntot) ? cnt[i] : 0;
    s[t] = v;
    __syncthreads();
    for (int off = 1; off < 256; off <<= 1) {
        int add = (t >= off) ? s[t - off] : 0;
        __syncthreads();
        s[t] += add;
        __syncthreads();
    }
    if (i < Ntot) {
        int r = partial[blockIdx.x] + s[t] - v;   // exclusive prefix
        rowptr[i] = r;
        cursor[i] = r;
    }
    if (i == 0) rowptr[Ntot] = Etot;
}

__global__ void k_scatter(const int* gdst, const int* pack, int* cursor, int* csr, int Etot) {
    int i = blockIdx.x * 256 + threadIdx.x;
    if (i >= Etot) return;
    int d = gdst[i];
    int pos = atomicAdd(&cursor[d], 1);
    csr[pos] = pack[i];
}

// ---------------- embedding + moment accumulation (grid-stride, 2 atomics/block) --
__global__ void k_embed(const float* x, const float* W, const float* b,
                        int F, int N, float* X, float* acc) {
    int j = threadIdx.x;   // 64
    float wj[8];
    for (int k = 0; k < F; k++) wj[k] = W[k * 64 + j];
    float bj = b[j];
    float s1 = 0.0f, s2 = 0.0f;
    for (int n = blockIdx.x; n < N; n += gridDim.x) {
        const float* xr = x + (size_t)n * F;
        float a = bj;
        for (int k = 0; k < F; k++) a += xr[k] * wj[k];
        X[(size_t)n * 64 + j] = a;
        s1 += a;
        s2 += a * a;
    }
    __shared__ float r1[64];
    __shared__ float r2[64];
    r1[j] = s1; r2[j] = s2;
    __syncthreads();
    for (int o = 32; o > 0; o >>= 1) {
        if (j < o) { r1[j] += r1[j + o]; r2[j] += r2[j + o]; }
        __syncthreads();
    }
    if (j == 0) { atomicAdd(&acc[0], r1[0]); atomicAdd(&acc[1], r2[0]); }
}

// ---------------- graph-norm over all N*64 elements of one node type ----------
__global__ void k_gnorm(float* X, const float* acc, const float* gamma,
                        const float* beta, int N) {
    int i = blockIdx.x * 256 + threadIdx.x;
    int tot = N * 64;
    if (i >= tot) return;
    float inv = 1.0f / (float)tot;
    float mu  = acc[0] * inv;
    float var = acc[1] * inv - mu * mu;
    float sd  = sqrtf(fmaxf(var, 0.0f));
    float sc  = 1.0f / (sd + 1e-5f);
    int j = i & 63;
    X[i] = (X[i] - mu) * sc * gamma[j] + beta[j];
}

// ---------------- KQV projection: [64] -> [192], one block/node ----------------
__global__ void k_kqv(const float* X, const float* Wkqv, const float* bkqv,
                      float* KQV, int N0, int N1, int l) {
    int n = blockIdx.x, j = threadIdx.x;   // 192 threads
    int t = (n < N0) ? 0 : ((n < N0 + N1) ? 1 : 2);
    const float* W = Wkqv + (size_t)(l * 3 + t) * 64 * 192;
    const float* b = bkqv + (size_t)(l * 3 + t) * 192;
    __shared__ float xs[64];
    if (j < 64) xs[j] = X[(size_t)n * 64 + j];
    __syncthreads();
    float a = b[j];
    for (int k = 0; k < 64; k++) a += xs[k] * W[k * 192 + j];
    KQV[(size_t)n * 192 + j] = a;
}

// ---------------- fused attention + aggregation: one wave per dst node ----------
// agg[n][h*8+ee] = (sum_edges ex * (v_src @ vrel)[h,ee]) / (sum_edges ex)
// ex = exp(q_dst . (k_src @ krel) * prel / sqrt(8)) — no max-shift (logits O(1)).
__global__ void k_attnagg(const float* KQV, const int* csr, const int* rowptr,
                          const float* krel_l, const float* vrel_l, const float* prel_l,
                          float* agg, int Ntot) {
    // LDS rel tables, stride 72 per (et,h) to break 8-way bank aliasing (h*72%32 = h*8)
    __shared__ float KRs[8 * 8 * 72];
    __shared__ float VRs[8 * 8 * 72];
    __shared__ float PRs[64];
    int tid = threadIdx.x;   // 256
    for (int i = tid; i < 4096; i += 256) {
        int eth = i >> 6, rest = i & 63;
        KRs[eth * 72 + rest] = krel_l[i];
        VRs[eth * 72 + rest] = vrel_l[i];
    }
    if (tid < 64) PRs[tid] = prel_l[tid];
    __syncthreads();

    int j = tid & 63, h = j >> 3, ee = j & 7;
    int wave  = blockIdx.x * 4 + (tid >> 6);
    int nwave = gridDim.x * 4;
    for (int n = wave; n < Ntot; n += nwave) {
        float qv = KQV[(size_t)n * 192 + 64 + j];
        float num = 0.0f, den = 0.0f;
        int e0 = rowptr[n], e1 = rowptr[n + 1];
        for (int idx = e0; idx < e1; idx++) {
            int pk = csr[idx];
            int sn = pk & 0xFFFFFF;
            int et = ((unsigned int)pk) >> 24;
            const float* kr = KQV + (size_t)sn * 192 + h * 8;
            const float* vr = kr + 128;
            const float* KR = KRs + (et * 8 + h) * 72;
            const float* VR = VRs + (et * 8 + h) * 72;
            float ke = 0.0f, ve = 0.0f;
#pragma unroll
            for (int d = 0; d < 8; d++) {
                float kd = kr[d], vd = vr[d];
                ke += kd * KR[d * 8 + ee];
                ve += vd * VR[d * 8 + ee];
            }
            float t = qv * ke;                  // reduce over ee within head group
            t += __shfl_xor(t, 1);
            t += __shfl_xor(t, 2);
            t += __shfl_xor(t, 4);
            float ex = expf(t * PRs[et * 8 + h] * 0.35355339059327373f);
            num += ex * ve;
            den += ex;
        }
        agg[(size_t)n * 64 + j] = (den > 0.0f) ? (num / den) : 0.0f;
    }
}

// ---------------- output projection + skip gate (in place) ----------------
__global__ void k_out(const float* agg, float* X, const float* Wout,
                      const float* bout, const float* skip, int N0, int N1, int l) {
    int n = blockIdx.x, j = threadIdx.x;   // 64 threads
    int t = (n < N0) ? 0 : ((n < N0 + N1) ? 1 : 2);
    const float* W = Wout + (size_t)(l * 3 + t) * 64 * 64;
    const float* b = bout + (size_t)(l * 3 + t) * 64;
    __shared__ float ga[64];
    float x = agg[(size_t)n * 64 + j];
    ga[j] = 0.5f * x * (1.0f + erff(x * 0.70710678118654752f));  // exact gelu
    float xold = X[(size_t)n * 64 + j];
    __syncthreads();
    float o = b[j];
    for (int k = 0; k < 64; k++) o += ga[k] * W[k * 64 + j];
    float gk = 1.0f / (1.0f + expf(-skip[l * 3 + t]));
    X[(size_t)n * 64 + j] = gk * o + (1.0f - gk) * xold;
}

// ---------------- global mean pooling (sum; divide in k_value) ----------------
__global__ void k_pool(const float* X, float* gsum, int N0, int N1, int N2) {
    int t = blockIdx.y, j = threadIdx.x;   // 64 threads
    int N   = (t == 0) ? N0 : ((t == 1) ? N1 : N2);
    int off = (t == 0) ? 0  : ((t == 1) ? N0 : N0 + N1);
    const float* base = X + (size_t)off * 64;
    float s = 0.0f;
    for (int r = blockIdx.x; r < N; r += gridDim.x) s += base[(size_t)r * 64 + j];
    atomicAdd(&gsum[t * 64 + j], s);
}

// ---------------- value head (one block, 192 threads) ----------------
__global__ void k_value(const float* gsum, float* gvec, const float* Wv1,
                        const float* bv1, const float* Wv2, const float* bv2,
                        float* out_val, int N0, int N1, int N2) {
    __shared__ float g[192];
    __shared__ float h1[64];
    int j = threadIdx.x;
    float Nd = (j < 64) ? (float)N0 : ((j < 128) ? (float)N1 : (float)N2);
    float gv = gsum[j] / Nd;
    g[j] = gv;
    gvec[j] = gv;
    __syncthreads();
    if (j < 64) {
        float a = bv1[j];
        for (int k = 0; k < 192; k++) a += g[k] * Wv1[k * 64 + j];
        h1[j] = fmaxf(a, 0.0f);
    }
    __syncthreads();
    if (j == 0) {
        float v = bv2[0];
        for (int k = 0; k < 64; k++) v += h1[k] * Wv2[k];
        out_val[0] = v;
    }
}

// ---------------- policy head (one block of 64 per pair) ----------------
__global__ void HGTPolicy_53051436040798_kernel(
        const float* X, const float* gvec, const int* op_idx, const int* m_idx,
        const float* Wp1, const float* bp1, const float* Wp2, const float* bp2,
        const float* Wp3, const float* bp3, float* out, int N0) {
    int p = blockIdx.x, j = threadIdx.x;   // 64 threads
    __shared__ float z[320];
    __shared__ float h1[64];
    __shared__ float h2[32];
    int on = op_idx[p], mn = m_idx[p];
    z[j]       = X[(size_t)on * 64 + j];
    z[64 + j]  = X[(size_t)(N0 + mn) * 64 + j];
    z[128 + j] = gvec[j];
    z[192 + j] = gvec[64 + j];
    z[256 + j] = gvec[128 + j];
    __syncthreads();
    float a = bp1[j];
    for (int k = 0; k < 320; k++) a += z[k] * Wp1[k * 64 + j];
    h1[j] = fmaxf(a, 0.0f);
    __syncthreads();
    if (j < 32) {
        float a2 = bp2[j];
        for (int k = 0; k < 64; k++) a2 += h1[k] * Wp2[k * 32 + j];
        h2[j] = fmaxf(a2, 0.0f);
    }
    __syncthreads();
    if (j == 0) {
        float lg = bp3[0];
        for (int k = 0; k < 32; k++) lg += h2[k] * Wp3[k];
        out[p] = lg;
    }
}

extern "C" void kernel_launch(void* const* d_in, const int* in_sizes, int n_in,
                              void* d_out, int out_size, void* d_ws, size_t ws_size,
                              hipStream_t stream) {
    const float* op_x      = (const float*)d_in[0];
    const float* machine_x = (const float*)d_in[1];
    const float* job_x     = (const float*)d_in[2];
    const float* W_op   = (const float*)d_in[3];
    const float* b_op   = (const float*)d_in[4];
    const float* W_mach = (const float*)d_in[5];
    const float* b_mach = (const float*)d_in[6];
    const float* W_job  = (const float*)d_in[7];
    const float* b_job  = (const float*)d_in[8];
    const float* ln_gamma = (const float*)d_in[9];
    const float* ln_beta  = (const float*)d_in[10];
    const float* Wkqv = (const float*)d_in[11];
    const float* bkqv = (const float*)d_in[12];
    const float* krel = (const float*)d_in[13];
    const float* vrel = (const float*)d_in[14];
    const float* prel = (const float*)d_in[15];
    const float* Wout = (const float*)d_in[16];
    const float* bout = (const float*)d_in[17];
    const float* skip = (const float*)d_in[18];
    const float* Wp1 = (const float*)d_in[19];
    const float* bp1 = (const float*)d_in[20];
    const float* Wp2 = (const float*)d_in[21];
    const float* bp2 = (const float*)d_in[22];
    const float* Wp3 = (const float*)d_in[23];
    const float* bp3 = (const float*)d_in[24];
    const float* Wv1 = (const float*)d_in[25];
    const float* bv1 = (const float*)d_in[26];
    const float* Wv2 = (const float*)d_in[27];
    const float* bv2 = (const float*)d_in[28];
    const int* op_idx = (const int*)d_in[37];
    const int* m_idx  = (const int*)d_in[38];

    const int NOP = in_sizes[0] / 8;
    const int NM  = in_sizes[1] / 7;
    const int NJ  = in_sizes[2] / 7;
    const int L   = in_sizes[11] / (3 * 64 * 192);
    const int P   = in_sizes[37];
    const int Ntot = NOP + NM + NJ;

    // EDGE_DEFS: (src_type, dst_type)
    const int sdef[8] = {2, 0, 0, 0, 0, 0, 1, 1};
    const int ddef[8] = {0, 2, 0, 0, 1, 1, 0, 0};
    const int toff[3] = {0, NOP, NOP + NM};
    const int* eptr[8];
    int Esz[8], eoff[9];
    eoff[0] = 0;
    for (int e = 0; e < 8; e++) {
        Esz[e] = in_sizes[29 + e] / 2;
        eptr[e] = (const int*)d_in[29 + e];
        eoff[e + 1] = eoff[e] + Esz[e];
    }
    const int Etot = eoff[8];

    // ---- workspace layout ----
    float* ws = (float*)d_ws;
    size_t o = 0;
    float* X    = ws + o; o += (size_t)Ntot * 64;
    float* KQV  = ws + o; o += (size_t)Ntot * 192;
    float* agg  = ws + o; o += (size_t)Ntot * 64;
    float* gsum = ws + o; o += 192;                 // gsum, gvec, nacc contiguous
    float* gvec = ws + o; o += 192;
    float* nacc = ws + o; o += 8;
    int* ib     = (int*)(ws + o);
    size_t io = 0;
    int* cnt    = ib + io; io += Ntot;
    int* rowptr = ib + io; io += Ntot + 1;
    int* cursor = ib + io; io += Ntot;
    int* partial= ib + io; io += 256;
    int* gdst   = ib + io; io += Etot;
    int* packs  = ib + io; io += Etot;
    int* csr    = ib + io; io += Etot;

    const int nchunks = (Ntot + 255) / 256;

    // ---- zero: cnt + small accumulators ----
    k_zero<<<64, 256, 0, stream>>>((unsigned int*)cnt, Ntot);
    k_zero<<<1, 256, 0, stream>>>((unsigned int*)gsum, 392);

    // ---- CSR build (same every launch) ----
    for (int e = 0; e < 8; e++) {
        k_flat<<<(Esz[e] + 255) / 256, 256, 0, stream>>>(
            eptr[e], Esz[e], toff[sdef[e]], toff[ddef[e]], e, eoff[e], gdst, packs, cnt);
    }
    k_scan1<<<nchunks, 256, 0, stream>>>(cnt, partial, Ntot);
    k_scan2<<<1, 64, 0, stream>>>(partial, nchunks);
    k_scan3<<<nchunks, 256, 0, stream>>>(cnt, partial, rowptr, cursor, Ntot, Etot);
    k_scatter<<<(Etot + 255) / 256, 256, 0, stream>>>(gdst, packs, cursor, csr, Etot);

    // ---- embed + per-type graph-norm ----
    k_embed<<<1024, 64, 0, stream>>>(op_x,      W_op,   b_op,   8, NOP, X,                           nacc + 0);
    k_embed<<<512,  64, 0, stream>>>(machine_x, W_mach, b_mach, 7, NM,  X + (size_t)NOP * 64,        nacc + 2);
    k_embed<<<512,  64, 0, stream>>>(job_x,     W_job,  b_job,  7, NJ,  X + (size_t)(NOP + NM) * 64, nacc + 4);

    k_gnorm<<<(NOP * 64 + 255) / 256, 256, 0, stream>>>(X, nacc + 0, ln_gamma, ln_beta, NOP);
    k_gnorm<<<(NM * 64 + 255) / 256, 256, 0, stream>>>(X + (size_t)NOP * 64, nacc + 2,
                                                       ln_gamma + 64, ln_beta + 64, NM);
    k_gnorm<<<(NJ * 64 + 255) / 256, 256, 0, stream>>>(X + (size_t)(NOP + NM) * 64, nacc + 4,
                                                       ln_gamma + 128, ln_beta + 128, NJ);

    // ---- HGT layers ----
    for (int l = 0; l < L; l++) {
        k_kqv<<<Ntot, 192, 0, stream>>>(X, Wkqv, bkqv, KQV, NOP, NM, l);
        k_attnagg<<<2048, 256, 0, stream>>>(KQV, csr, rowptr,
                                            krel + (size_t)l * 4096,
                                            vrel + (size_t)l * 4096,
                                            prel + (size_t)l * 64,
                                            agg, Ntot);
        k_out<<<Ntot, 64, 0, stream>>>(agg, X, Wout, bout, skip, NOP, NM, l);
    }

    // ---- pooling + heads ----
    dim3 pg(64, 3);
    k_pool<<<pg, 64, 0, stream>>>(X, gsum, NOP, NM, NJ);
    k_value<<<1, 192, 0, stream>>>(gsum, gvec, Wv1, bv1, Wv2, bv2,
                                   (float*)d_out + P, NOP, NM, NJ);
    HGTPolicy_53051436040798_kernel<<<P, 64, 0, stream>>>(
        X, gvec, op_idx, m_idx, Wp1, bp1, Wp2, bp2, Wp3, bp3, (float*)d_out, NOP);
}